// Round 1
// baseline (279.736 us; speedup 1.0000x reference)
//
#include <hip/hip_runtime.h>
#include <math.h>

#define B_ 8
#define T_ 4096
#define D_ 192
#define E_ 6
#define H_ 768            // 4*D
#define NTOK (B_*T_)      // 32768
#define TT 16             // tokens per block
#define NT 3              // number of expert types

// ws float-offset layout
#define WS_TPART 0                  // 3*768 (rb1 folded in)
#define WS_W2M   (NT*H_)            // 768
#define WS_TEMP  (WS_W2M + H_)      // 1
#define WS_RB2M  (WS_TEMP + 1)      // 1
#define WS_ENT   (WS_RB2M + 1)      // 1 (float accumulator, zeroed each call)
#define WS_LOAD  (WS_ENT + 1)       // 6 uints (zeroed each call)

__device__ __forceinline__ float gelu_f(float v) {
    // exact gelu: 0.5*v*(1+erf(v/sqrt(2)))
    return 0.5f * v * (1.0f + erff(v * 0.70710678118654752440f));
}
__device__ __forceinline__ float softplus_f(float x) {
    // jax.nn.softplus = logaddexp(x, 0) = max(x,0) + log1p(exp(-|x|))
    return fmaxf(x, 0.0f) + log1pf(expf(-fabsf(x)));
}

__global__ __launch_bounds__(256) void prep_kernel(
    const float* __restrict__ type_emb,    // (3, 384)
    const float* __restrict__ rw1,         // (576, 768)
    const float* __restrict__ rb1,         // (768)
    const float* __restrict__ rw2,         // (768, 6)
    const float* __restrict__ rb2,         // (6)
    const float* __restrict__ temperature, // (1)
    float* __restrict__ wsF)
{
    int blk = blockIdx.x, tid = threadIdx.x;
    if (blk < 9) {
        // tpart[c][j] = sum_k type_emb[c][k] * rw1[192+k][j] + rb1[j]
        int o = blk * 256 + tid;          // 0..2303
        int c = o / H_, j = o % H_;
        float s = rb1[j];
        const float* te = type_emb + c * (2 * D_);
        #pragma unroll 4
        for (int k = 0; k < 2 * D_; ++k)
            s = fmaf(te[k], rw1[(size_t)(D_ + k) * H_ + j], s);
        wsF[WS_TPART + o] = s;
    } else {
        for (int j = tid; j < H_; j += 256) {
            float s = 0.f;
            #pragma unroll
            for (int e = 0; e < E_; ++e) s += rw2[(size_t)j * E_ + e];
            wsF[WS_W2M + j] = s * (1.0f / 6.0f);
        }
        if (tid == 0) {
            float decay = (float)pow(0.95, (double)(T_ / 100));   // 0.95^40
            float tv = temperature[0] * decay;
            tv = fminf(fmaxf(tv, 0.05f), 3.0f);
            wsF[WS_TEMP] = tv;
            float rs = 0.f;
            #pragma unroll
            for (int e = 0; e < E_; ++e) rs += rb2[e];
            wsF[WS_RB2M] = rs * (1.0f / 6.0f);
            wsF[WS_ENT] = 0.f;
            unsigned* lu = (unsigned*)(wsF + WS_LOAD);
            #pragma unroll
            for (int e = 0; e < E_; ++e) lu[e] = 0u;
        }
    }
}

__global__ __launch_bounds__(256, 2) void router_main(
    const float* __restrict__ x,            // (32768, 192)
    const float* __restrict__ noise,        // (32768, 6)
    const int*   __restrict__ expert_types, // (6)
    const float* __restrict__ nw1,          // (192, 12)
    const float* __restrict__ nb1,          // (12)
    const float* __restrict__ nw2,          // (12, 6)
    const float* __restrict__ nb2,          // (6)
    const float* __restrict__ rw1,          // wx = rows [0,192)
    float* __restrict__ wsF,
    float* __restrict__ out)                // p | idx(float) | aux
{
    __shared__ float xsT[D_][TT];       // 12 KB, transposed x tile
    __shared__ float xp[TT][H_];        // 48 KB
    __shared__ float tp[NT * H_];       // 9 KB
    __shared__ float w2m[H_];           // 3 KB
    __shared__ float logits[TT][NT];
    __shared__ float h1[TT][12];
    __shared__ float noisy[TT][E_];
    __shared__ float ps[TT][2];
    __shared__ int   is_[TT][2];
    __shared__ float entArr[TT];
    __shared__ unsigned loadLds[E_];

    int tid = threadIdx.x;
    int tok0 = blockIdx.x * TT;

    // ---- stage x tile (contiguous 3072 floats), tp, w2m
    for (int i = tid; i < TT * D_; i += 256) {
        int t = i / D_, k = i % D_;
        xsT[k][t] = x[(size_t)tok0 * D_ + i];
    }
    for (int i = tid; i < NT * H_; i += 256) tp[i] = wsF[WS_TPART + i];
    for (int i = tid; i < H_; i += 256)      w2m[i] = wsF[WS_W2M + i];
    if (tid < E_) loadLds[tid] = 0u;
    __syncthreads();

    // ---- phase 1: xp(16x768) = xtile(16x192) @ wx(192x768)
    // each thread: cols {tid, tid+256, tid+512} x 16 tokens (48 accumulators)
    float a0[TT], a1[TT], a2[TT];
    #pragma unroll
    for (int t = 0; t < TT; ++t) { a0[t] = 0.f; a1[t] = 0.f; a2[t] = 0.f; }
    #pragma unroll 2
    for (int k = 0; k < D_; ++k) {
        float w0 = rw1[(size_t)k * H_ + tid];
        float w1 = rw1[(size_t)k * H_ + tid + 256];
        float w2 = rw1[(size_t)k * H_ + tid + 512];
        #pragma unroll
        for (int t = 0; t < TT; ++t) {
            float xv = xsT[k][t];                 // LDS broadcast
            a0[t] = fmaf(xv, w0, a0[t]);
            a1[t] = fmaf(xv, w1, a1[t]);
            a2[t] = fmaf(xv, w2, a2[t]);
        }
    }
    #pragma unroll
    for (int t = 0; t < TT; ++t) {
        xp[t][tid]       = a0[t];
        xp[t][tid + 256] = a1[t];
        xp[t][tid + 512] = a2[t];
    }
    __syncthreads();

    // ---- phase 2: logits[t][c] = sum_j gelu(xp+tp)*w2m + rb2m  (3 types only)
    int wave = tid >> 6, lane = tid & 63;
    float rb2m = wsF[WS_RB2M];
    for (int p = wave * 12; p < wave * 12 + 12; ++p) {   // 48 pairs over 4 waves
        int t = p / NT, c = p % NT;
        float s = 0.f;
        #pragma unroll
        for (int ji = 0; ji < H_ / 64; ++ji) {
            int j = lane + ji * 64;
            float v = xp[t][j] + tp[c * H_ + j];
            s = fmaf(gelu_f(v), w2m[j], s);
        }
        #pragma unroll
        for (int off = 32; off; off >>= 1) s += __shfl_xor(s, off, 64);
        if (lane == 0) logits[t][c] = s + rb2m;
    }
    __syncthreads();

    // ---- phase 3: noise MLP, noisy logits, top-2, softmax, entropy
    int t = tid >> 4, j = tid & 15;       // 16 threads per token
    if (j < 12) {
        float s = nb1[j];
        for (int k = 0; k < D_; ++k) s = fmaf(xsT[k][t], nw1[k * 12 + j], s);
        h1[t][j] = gelu_f(s);
    }
    __syncthreads();
    float temp = wsF[WS_TEMP];
    if (j < E_) {
        float s = nb2[j];
        #pragma unroll
        for (int i = 0; i < 12; ++i) s = fmaf(h1[t][i], nw2[i * E_ + j], s);
        float nsc = softplus_f(softplus_f(s));
        int ety = expert_types[j];
        float nv = logits[t][ety] + ((ety == 1) ? 0.3f : 0.0f)
                 + temp * (noise[(size_t)(tok0 + t) * E_ + j] * nsc);
        noisy[t][j] = nv;
    }
    __syncthreads();
    if (j == 0) {
        // top-2, ties -> lower index first (strict > keeps earliest)
        float v1 = -1e30f; int i1 = 0;
        #pragma unroll
        for (int e = 0; e < E_; ++e) {
            float v = noisy[t][e];
            if (v > v1) { v1 = v; i1 = e; }
        }
        float v2 = -1e30f; int i2 = 0;
        #pragma unroll
        for (int e = 0; e < E_; ++e) {
            if (e == i1) continue;
            float v = noisy[t][e];
            if (v > v2) { v2 = v; i2 = e; }
        }
        float e2 = expf(v2 - v1);
        float denom = 1.0f + e2;
        float p1 = 1.0f / denom;
        float p2 = e2 / denom;
        ps[t][0] = p1; ps[t][1] = p2;
        is_[t][0] = i1; is_[t][1] = i2;
        entArr[t] = -(p1 * logf(p1 + 1e-8f) + p2 * logf(p2 + 1e-8f));
        atomicAdd(&loadLds[i1], 1u);
        atomicAdd(&loadLds[i2], 1u);
    }
    __syncthreads();

    // ---- outputs
    for (int i = tid; i < TT * E_; i += 256) {
        int tt = i / E_, e = i % E_;
        float v = 0.f;
        if (e == is_[tt][0])      v = ps[tt][0];
        else if (e == is_[tt][1]) v = ps[tt][1];
        out[(size_t)tok0 * E_ + i] = v;
    }
    if (tid < TT * 2) {
        int tt = tid >> 1, s = tid & 1;
        out[(size_t)NTOK * E_ + (size_t)(tok0 + tt) * 2 + s] = (float)is_[tt][s];
    }
    if (tid == 0) {
        float es = 0.f;
        #pragma unroll
        for (int tt = 0; tt < TT; ++tt) es += entArr[tt];
        atomicAdd(&wsF[WS_ENT], es);
        unsigned* lu = (unsigned*)(wsF + WS_LOAD);
        #pragma unroll
        for (int e = 0; e < E_; ++e)
            if (loadLds[e]) atomicAdd(&lu[e], loadLds[e]);
    }
}

__global__ void finalize_kernel(const float* __restrict__ wsF,
                                float* __restrict__ out)
{
    if (threadIdx.x == 0 && blockIdx.x == 0) {
        const unsigned* lu = (const unsigned*)(wsF + WS_LOAD);
        double m = 0.0, l[E_];
        #pragma unroll
        for (int e = 0; e < E_; ++e) { l[e] = (double)lu[e]; m += l[e]; }
        m /= (double)E_;
        double var = 0.0;
        #pragma unroll
        for (int e = 0; e < E_; ++e) { double d = l[e] - m; var += d * d; }
        var /= (double)(E_ - 1);
        double stdl = sqrt(var);
        // importance = em.sum(0).mean(1) == 8*2/6 for every t -> std == 0 exactly
        double ent = (double)wsF[WS_ENT] / (double)NTOK;
        out[(size_t)NTOK * E_ + (size_t)NTOK * 2] = (float)(0.1 * ent + 0.2 * stdl);
    }
}

extern "C" void kernel_launch(void* const* d_in, const int* in_sizes, int n_in,
                              void* d_out, int out_size, void* d_ws, size_t ws_size,
                              hipStream_t stream)
{
    const float* x            = (const float*)d_in[0];
    const float* noise        = (const float*)d_in[1];
    const int*   expert_types = (const int*)  d_in[2];
    const float* type_emb     = (const float*)d_in[3];
    const float* nw1          = (const float*)d_in[4];
    const float* nb1          = (const float*)d_in[5];
    const float* nw2          = (const float*)d_in[6];
    const float* nb2          = (const float*)d_in[7];
    const float* rw1          = (const float*)d_in[8];
    const float* rb1          = (const float*)d_in[9];
    const float* rw2          = (const float*)d_in[10];
    const float* rb2          = (const float*)d_in[11];
    const float* temperature  = (const float*)d_in[12];
    float* out = (float*)d_out;
    float* wsF = (float*)d_ws;

    prep_kernel<<<10, 256, 0, stream>>>(type_emb, rw1, rb1, rw2, rb2, temperature, wsF);
    router_main<<<NTOK / TT, 256, 0, stream>>>(x, noise, expert_types,
                                               nw1, nb1, nw2, nb2, rw1, wsF, out);
    finalize_kernel<<<1, 64, 0, stream>>>(wsF, out);
}